// Round 16
// baseline (107.566 us; speedup 1.0000x reference)
//
#include <hip/hip_runtime.h>
#include <hip/hip_bf16.h>

// Problem constants (fixed by setup_inputs): B=4, S=2048, H=16, DH=64, W=4,
// Kc=512, D=1024. Output (4,2048,1024) f32.

typedef __attribute__((ext_vector_type(8))) short short8;   // 8 bf16 (4 VGPRs)
typedef __attribute__((ext_vector_type(4))) short short4v;  // 4 bf16 (2 VGPRs)
typedef __attribute__((ext_vector_type(4))) float f32x4;
typedef __attribute__((ext_vector_type(4))) int int4e;
typedef __attribute__((ext_vector_type(2))) unsigned int u32x2;

#define MFMA32(A, Bf, C) __builtin_amdgcn_mfma_f32_16x16x32_bf16((A), (Bf), (C), 0, 0, 0)
#define MFMA16(A, Bf, C) __builtin_amdgcn_mfma_f32_16x16x16bf16_1k((A), (Bf), (C), 0, 0, 0)

static __device__ __forceinline__ unsigned short f2bf(float f) {
  unsigned int u = __builtin_bit_cast(unsigned int, f);
  u += 0x7fffu + ((u >> 16) & 1u);   // RNE (finite inputs only)
  return (unsigned short)(u >> 16);
}
static __device__ __forceinline__ unsigned int pack2c(float a, float b) {
  unsigned short lo = __builtin_bit_cast(unsigned short, __float2bfloat16(a));
  unsigned short hi = __builtin_bit_cast(unsigned short, __float2bfloat16(b));
  return (unsigned int)lo | ((unsigned int)hi << 16);
}
// 4x f32 -> 4x bf16 via packed-pair conversions (v_cvt_pk_bf16_f32)
static __device__ __forceinline__ short4v pk4(float a, float b, float c, float d) {
  u32x2 t;
  t[0] = pack2c(a, b);
  t[1] = pack2c(c, d);
  return __builtin_bit_cast(short4v, t);
}
// masked exp2: exp2(s) if bit set, else 0 — sign-extended bit AND
// (v_bfe_i32 + v_and; robust even if exp2 overflows on masked lanes).
static __device__ __forceinline__ float mexp2(float s, unsigned int w, int bit) {
  const unsigned int m = (unsigned int)(((int)(w << (31 - bit))) >> 31);
  const float e = __builtin_amdgcn_exp2f(s);
  return __builtin_bit_cast(float, __builtin_bit_cast(unsigned int, e) & m);
}
static __device__ __forceinline__ short8 cvt8(f32x4 lo, f32x4 hi) {
  short8 r;
  r[0] = (short)f2bf(lo[0]); r[1] = (short)f2bf(lo[1]);
  r[2] = (short)f2bf(lo[2]); r[3] = (short)f2bf(lo[3]);
  r[4] = (short)f2bf(hi[0]); r[5] = (short)f2bf(hi[1]);
  r[6] = (short)f2bf(hi[2]); r[7] = (short)f2bf(hi[3]);
  return r;
}
static __device__ __forceinline__ short8 cvt8s(f32x4 lo, f32x4 hi, float s) {
  short8 r;
  r[0] = (short)f2bf(lo[0]*s); r[1] = (short)f2bf(lo[1]*s);
  r[2] = (short)f2bf(lo[2]*s); r[3] = (short)f2bf(lo[3]*s);
  r[4] = (short)f2bf(hi[0]*s); r[5] = (short)f2bf(hi[1]*s);
  r[6] = (short)f2bf(hi[2]*s); r[7] = (short)f2bf(hi[3]*s);
  return r;
}
// async global -> LDS, 16B/lane; LDS dest is wave-uniform base + lane*16
static __device__ __forceinline__ void gl_lds16(const void* g, void* l) {
  __builtin_amdgcn_global_load_lds(
      (const __attribute__((address_space(1))) unsigned int*)g,
      (__attribute__((address_space(3))) unsigned int*)l, 16, 0, 0);
}

// ---------------------------------------------------------------------------
// 1) Fused pre: [0,1024) conv1d compression (self-transposing); [1024,1280)
// transpose W; [1280,1792) pack mask bits.
__global__ __launch_bounds__(256) void pre_kernel(
    const float* __restrict__ srcK, const float* __restrict__ kckRaw,
    const float* __restrict__ biasK, unsigned short* __restrict__ dstK,
    const float* __restrict__ srcV, const float* __restrict__ vckRaw,
    const float* __restrict__ biasV, unsigned short* __restrict__ dstV,
    const float* __restrict__ W, unsigned short* __restrict__ WT,
    const int* __restrict__ msk, unsigned int* __restrict__ mpk) {
  __shared__ unsigned short shm[21504];          // 43008 B
  const int bid = blockIdx.x;
  const int tid = threadIdx.x;
  if (bid < 1024) {
    const int tpose = bid >> 9;
    const float* src = tpose ? srcV : srcK;
    const float* kraw = tpose ? vckRaw : kckRaw;
    const float* bias = tpose ? biasV : biasK;
    unsigned short* dst = tpose ? dstV : dstK;
    unsigned short* kTl = shm;                   // [o=64][kk=256 pad 264]
    unsigned short* t = shm + 16896;             // [64][72] epilogue tile
    {
      const int o = tid & 63, m0 = tid >> 6;
      #pragma unroll
      for (int it = 0; it < 8; ++it) {
        const int kk0 = (it * 4 + m0) * 8;
        short8 v;
        #pragma unroll
        for (int s = 0; s < 8; ++s)
          v[s] = (short)f2bf(kraw[(size_t)(kk0 + s) * 64 + o]);
        *(short8*)(kTl + o * 264 + kk0) = v;
      }
    }
    __syncthreads();
    const int wid = tid >> 6, lane = tid & 63;
    const int q = lane & 15, g = lane >> 4;
    const int blockR0 = (bid & 511) * 64;
    const int R0 = blockR0 + wid * 16;
    const int row = R0 + q;
    const int bh = row >> 9, c = row & 511;
    const int b = bh >> 4, h = bh & 15;
    const float* sb = src + (((size_t)b * 2048 + (size_t)c * 4) * 16 + h) * 64;
    f32x4 acc[4];
    #pragma unroll
    for (int ct = 0; ct < 4; ++ct) acc[ct] = f32x4{0.f, 0.f, 0.f, 0.f};
    #pragma unroll
    for (int ch = 0; ch < 8; ++ch) {
      const int kk = ch * 32 + g * 8;
      const int w = kk >> 6, i = kk & 63;
      const float* s8 = sb + (size_t)w * 1024 + i;
      short8 a = cvt8(*(const f32x4*)s8, *(const f32x4*)(s8 + 4));
      #pragma unroll
      for (int ct = 0; ct < 4; ++ct) {
        short8 bf = *(const short8*)(kTl + (ct * 16 + q) * 264 + ch * 32 + g * 8);
        acc[ct] = MFMA32(a, bf, acc[ct]);
      }
    }
    #pragma unroll
    for (int ct = 0; ct < 4; ++ct) {
      const int col = ct * 16 + q;
      const float bv = bias[col];
      #pragma unroll
      for (int r = 0; r < 4; ++r) {
        const int lr = wid * 16 + 4 * g + r;
        const unsigned short val = f2bf(acc[ct][r] + bv);
        t[tpose ? (col * 72 + lr) : (lr * 72 + col)] = val;
      }
    }
    __syncthreads();
    const int d = tid >> 2, sq = tid & 3;
    const short8 w0 = *(const short8*)(&t[d * 72 + sq * 16]);
    const short8 w1 = *(const short8*)(&t[d * 72 + sq * 16 + 8]);
    unsigned short* op;
    if (tpose) {
      const int bhb = blockR0 >> 9, cb = blockR0 & 511;
      op = dst + (size_t)bhb * 32768 + (size_t)d * 512 + cb + sq * 16;
    } else {
      op = dst + (size_t)(blockR0 + d) * 64 + sq * 16;
    }
    *(short8*)op = w0;
    *(short8*)(op + 8) = w1;
  } else if (bid < 1280) {
    unsigned short (*t2)[72] = (unsigned short (*)[72])shm;
    const int wb = bid - 1024;
    const int k0 = (wb & 15) * 64, n0 = (wb >> 4) * 64;
    const int cr = tid >> 4, cc = (tid & 15) * 4;
    #pragma unroll
    for (int it = 0; it < 4; ++it) {
      const int kk = it * 16 + cr;
      const f32x4 v = *(const f32x4*)(W + (size_t)(k0 + kk) * 1024 + n0 + cc);
      #pragma unroll
      for (int j = 0; j < 4; ++j) t2[cc + j][kk] = f2bf(v[j]);
    }
    __syncthreads();
    const int rn = tid >> 2, seg = tid & 3;
    const short8 w0 = *(const short8*)(&t2[rn][seg * 16]);
    const short8 w1 = *(const short8*)(&t2[rn][seg * 16 + 8]);
    unsigned short* op = WT + (size_t)(n0 + rn) * 1024 + k0 + seg * 16;
    *(short8*)op = w0;
    *(short8*)(op + 8) = w1;
  } else {
    const int w = (bid - 1280) * 256 + tid;
    const int* p = msk + (size_t)w * 32;
    unsigned int b = 0;
    #pragma unroll
    for (int i = 0; i < 8; ++i) {
      const int4e v = *(const int4e*)(p + i * 4);
      b |= (unsigned int)(v[0] & 1) << (i * 4);
      b |= (unsigned int)(v[1] & 1) << (i * 4 + 1);
      b |= (unsigned int)(v[2] & 1) << (i * 4 + 2);
      b |= (unsigned int)(v[3] & 1) << (i * 4 + 3);
    }
    mpk[w] = b;
  }
}

// ---------------------------------------------------------------------------
// 3) Attention v16 = v15 + bfe/and masked-exp (2 VALU/elem vs 4).
__global__ __launch_bounds__(256) void attn_kernel(
    const float* __restrict__ preq, const unsigned int* __restrict__ mpk,
    const unsigned short* __restrict__ kc, const unsigned short* __restrict__ vt,
    unsigned short* __restrict__ merged) {
  __shared__ unsigned short shm[18432];   // 36864 B: K 2x4608sh | V 2x4608sh
  unsigned short* Kl = shm;
  unsigned short* Vl = shm + 9216;
  const int tid = threadIdx.x;
  const int wid = tid >> 6, lane = tid & 63;
  const int q = lane & 15, g = lane >> 4;
  const int bid = blockIdx.x;
  const int x = bid & 7, ii = bid >> 3;
  const int bp = x >> 1;
  const int hp = ((x & 1) << 3) | (ii & 7);
  const int tile = ii >> 3;
  const int jj = hp * 4 + bp;
  const int bin = jj >> 4, hin = jj & 15;
  const int s0 = tile * 128 + wid * 32;

  const float QS = 0.18033688f;    // 0.125 * log2(e)
  const float* qpA = preq + (((size_t)bin * 2048 + s0 + q) * 16 + hin) * 64;
  const float* qpB = qpA + 16 * 1024;
  const short8 bqA0 = cvt8s(*(const f32x4*)(qpA + g * 8), *(const f32x4*)(qpA + g * 8 + 4), QS);
  const short8 bqA1 = cvt8s(*(const f32x4*)(qpA + 32 + g * 8), *(const f32x4*)(qpA + 32 + g * 8 + 4), QS);
  const short8 bqB0 = cvt8s(*(const f32x4*)(qpB + g * 8), *(const f32x4*)(qpB + g * 8 + 4), QS);
  const short8 bqB1 = cvt8s(*(const f32x4*)(qpB + 32 + g * 8), *(const f32x4*)(qpB + 32 + g * 8 + 4), QS);

  const unsigned short* kcb = kc + (size_t)jj * 512 * 64;
  const unsigned short* vtb = vt + (size_t)(bp * 16 + hp) * 64 * 512;
  const unsigned int* mrowA = mpk + ((size_t)bp * 2048 + s0 + q) * 16;
  const unsigned int* mrowB = mrowA + 256;

  const int sr = tid >> 3, sseg = tid & 7;
  const unsigned short* gK0 = kcb + (size_t)sr * 64 + sseg * 8;
  const unsigned short* gK1 = gK0 + 32 * 64;
  unsigned short* lK0 = Kl + sr * 72 + sseg * 8;
  unsigned short* lK1 = lK0 + 32 * 72;
  const unsigned short* gV0 = vtb + (size_t)sr * 512 + sseg * 8;
  const unsigned short* gV1 = gV0 + 32 * 512;
  unsigned short* lV0 = Vl + sr * 72 + sseg * 8;
  unsigned short* lV1 = lV0 + 32 * 72;

  const short4v one4 = {(short)0x3F80, (short)0x3F80, (short)0x3F80, (short)0x3F80};

  f32x4 oA[4], oB[4];
  #pragma unroll
  for (int o = 0; o < 4; ++o) { oA[o] = f32x4{0,0,0,0}; oB[o] = f32x4{0,0,0,0}; }
  f32x4 oSA = {0,0,0,0}, oSB = {0,0,0,0};

  *(short8*)lK0 = *(const short8*)gK0;
  *(short8*)lK1 = *(const short8*)gK1;
  *(short8*)lV0 = *(const short8*)gV0;
  *(short8*)lV1 = *(const short8*)gV1;
  u32x2 mA2 = *(const u32x2*)mrowA;
  u32x2 mB2 = *(const u32x2*)mrowB;
  __syncthreads();

  #pragma unroll 2
  for (int sc = 0; sc < 8; ++sc) {
    short8 nK0, nK1, nV0, nV1;
    u32x2 nmA = {0, 0}, nmB = {0, 0};
    if (sc < 7) {
      nK0 = *(const short8*)(gK0 + (size_t)(sc + 1) * 4096);
      nK1 = *(const short8*)(gK1 + (size_t)(sc + 1) * 4096);
      nV0 = *(const short8*)(gV0 + (sc + 1) * 64);
      nV1 = *(const short8*)(gV1 + (sc + 1) * 64);
      nmA = *(const u32x2*)(mrowA + 2 * (sc + 1));
      nmB = *(const u32x2*)(mrowB + 2 * (sc + 1));
    }
    const unsigned short* Kc_ = Kl + (sc & 1) * 4608;
    const unsigned short* Vc_ = Vl + (sc & 1) * 4608;
    __builtin_amdgcn_s_setprio(1);
    short4v pA[4], pB[4];
    #pragma unroll
    for (int sub = 0; sub < 4; ++sub) {
      const short8 k0 = *(const short8*)(Kc_ + (sub * 16 + q) * 72 + g * 8);
      const short8 k1 = *(const short8*)(Kc_ + (sub * 16 + q) * 72 + 32 + g * 8);
      f32x4 sA = {0,0,0,0}; sA = MFMA32(k0, bqA0, sA); sA = MFMA32(k1, bqA1, sA);
      f32x4 sB = {0,0,0,0}; sB = MFMA32(k0, bqB0, sB); sB = MFMA32(k1, bqB1, sB);
      const unsigned int wA = mA2[sub >> 1], wB = mB2[sub >> 1];
      const int bb = (sub & 1) * 16 + 4 * g;
      float eA[4], eB[4];
      #pragma unroll
      for (int r = 0; r < 4; ++r) {
        eA[r] = mexp2(sA[r], wA, bb + r);
        eB[r] = mexp2(sB[r], wB, bb + r);
      }
      pA[sub] = pk4(eA[0], eA[1], eA[2], eA[3]);
      pB[sub] = pk4(eB[0], eB[1], eB[2], eB[3]);
    }
    #pragma unroll
    for (int o = 0; o < 4; ++o) {
      #pragma unroll
      for (int sub = 0; sub < 4; ++sub) {
        const short4v vfr = *(const short4v*)(Vc_ + (o * 16 + q) * 72 + sub * 16 + g * 4);
        oA[o] = MFMA16(vfr, pA[sub], oA[o]);
        oB[o] = MFMA16(vfr, pB[sub], oB[o]);
      }
    }
    #pragma unroll
    for (int sub = 0; sub < 4; ++sub) {
      oSA = MFMA16(one4, pA[sub], oSA);
      oSB = MFMA16(one4, pB[sub], oSB);
    }
    __builtin_amdgcn_s_setprio(0);
    if (sc < 7) {
      const int nb = ((sc + 1) & 1) * 4608;
      *(short8*)(lK0 + nb) = nK0;
      *(short8*)(lK1 + nb) = nK1;
      *(short8*)(lV0 + nb) = nV0;
      *(short8*)(lV1 + nb) = nV1;
    }
    __syncthreads();
    mA2 = nmA; mB2 = nmB;
  }

  const float rlA = 1.0f / oSA[0], rlB = 1.0f / oSB[0];

  unsigned short* eb = shm + wid * 2304;
  #pragma unroll
  for (int qs = 0; qs < 2; ++qs) {
    unsigned int* U = (unsigned int*)(eb + qs * 1152);
    const float rl = qs ? rlB : rlA;
    #pragma unroll
    for (int o = 0; o < 4; ++o) {
      const f32x4 ov = qs ? oB[o] : oA[o];
      U[q * 36 + o * 8 + 2 * g]     = pack2c(ov[0] * rl, ov[1] * rl);
      U[q * 36 + o * 8 + 2 * g + 1] = pack2c(ov[2] * rl, ov[3] * rl);
    }
  }
  const int ir = lane >> 2, sg2 = lane & 3;
  #pragma unroll
  for (int qs = 0; qs < 2; ++qs) {
    const unsigned short* ep = eb + qs * 1152;
    const short8 w0 = *(const short8*)(ep + ir * 72 + sg2 * 16);
    const short8 w1 = *(const short8*)(ep + ir * 72 + sg2 * 16 + 8);
    unsigned short* mp = merged + ((size_t)(bp * 2048 + s0 + qs * 16 + ir)) * 1024 + hp * 64 + sg2 * 16;
    *(short8*)mp = w0;
    *(short8*)(mp + 8) = w1;
  }
}

// ---------------------------------------------------------------------------
// 4) Output projection v16: 128x64 tiles, grid 1024 (removes the 2-block/CU
// grid cap; B traffic unchanged). One gl_lds16 per thread per k-step (4KB),
// distance-2 pipeline, one barrier per 2 k-steps. Staging dest = linear
// tid*16 per block buffer; source pre-swizzled to match read-side XOR.
__global__ __launch_bounds__(256) void gemm_kernel(
    const unsigned short* __restrict__ A, const unsigned short* __restrict__ BT,
    float* __restrict__ out) {
  __shared__ unsigned short Bb[4][2048];   // 4 bufs x (64 n x 64B)
  const int tid = threadIdx.x;
  const int wid = tid >> 6, lane = tid & 63;
  const int q = lane & 15, g = lane >> 4;
  const int bid = blockIdx.x;
  const int x = bid & 7, i = bid >> 3;      // i in 0..127
  const int N0 = (i & 15) * 64;
  const int M0 = (x * 8 + (i >> 4)) * 128 + wid * 32;

  // staging source: thread tid fills LDS bytes [tid*16, tid*16+16) =
  // row r0 = tid>>2, byte-col (tid&3)*16, pre-swizzled.
  const int r0 = tid >> 2;
  const int sc = (tid & 3) * 16;
  const int b0 = sc ^ (((r0 >> 2) & 3) << 4);
  const unsigned short* gs0 = BT + (size_t)(N0 + r0) * 1024 + (b0 >> 1);
  const int bsz = ((q >> 2) & 3) << 4;

  f32x4 acc[2][4];
  #pragma unroll
  for (int rt = 0; rt < 2; ++rt)
    #pragma unroll
    for (int ct = 0; ct < 4; ++ct) acc[rt][ct] = f32x4{0.f, 0.f, 0.f, 0.f};
  const unsigned short* a0p = A + (size_t)(M0 + q) * 1024 + g * 8;
  const unsigned short* a1p = a0p + 16 * 1024;

  gl_lds16(gs0,      (char*)&Bb[0][0] + tid * 16);
  gl_lds16(gs0 + 32, (char*)&Bb[1][0] + tid * 16);
  short8 aC00 = *(const short8*)(a0p);
  short8 aC01 = *(const short8*)(a1p);
  short8 aC10 = *(const short8*)(a0p + 32);
  short8 aC11 = *(const short8*)(a1p + 32);
  __syncthreads();

  for (int t = 0; t < 32; t += 2) {
    if (t < 30) {
      gl_lds16(gs0 + (t + 2) * 32, (char*)&Bb[(t + 2) & 3][0] + tid * 16);
      gl_lds16(gs0 + (t + 3) * 32, (char*)&Bb[(t + 3) & 3][0] + tid * 16);
    }
    short8 aN00 = aC00, aN01 = aC01, aN10 = aC10, aN11 = aC11;
    if (t < 30) {
      aN00 = *(const short8*)(a0p + (t + 2) * 32);
      aN01 = *(const short8*)(a1p + (t + 2) * 32);
      aN10 = *(const short8*)(a0p + (t + 3) * 32);
      aN11 = *(const short8*)(a1p + (t + 3) * 32);
    }
    const unsigned short* Bc0 = &Bb[t & 3][0];
    const unsigned short* Bc1 = &Bb[(t + 1) & 3][0];
    #pragma unroll
    for (int ct = 0; ct < 4; ++ct) {
      const int off = (ct * 16 + q) * 32 + (((g * 16) ^ bsz) >> 1);
      const short8 bfr0 = *(const short8*)(Bc0 + off);
      acc[0][ct] = MFMA32(aC00, bfr0, acc[0][ct]);
      acc[1][ct] = MFMA32(aC01, bfr0, acc[1][ct]);
      const short8 bfr1 = *(const short8*)(Bc1 + off);
      acc[0][ct] = MFMA32(aC10, bfr1, acc[0][ct]);
      acc[1][ct] = MFMA32(aC11, bfr1, acc[1][ct]);
    }
    aC00 = aN00; aC01 = aN01; aC10 = aN10; aC11 = aN11;
    __syncthreads();
  }
  #pragma unroll
  for (int rt = 0; rt < 2; ++rt)
    #pragma unroll
    for (int ct = 0; ct < 4; ++ct)
      #pragma unroll
      for (int r = 0; r < 4; ++r)
        out[(size_t)(M0 + rt * 16 + 4 * g + r) * 1024 + N0 + ct * 16 + q] = acc[rt][ct][r];
}

// ---------------------------------------------------------------------------
extern "C" void kernel_launch(void* const* d_in, const int* in_sizes, int n_in,
                              void* d_out, int out_size, void* d_ws, size_t ws_size,
                              hipStream_t stream) {
  const float* preq = (const float*)d_in[0];
  const float* prev = (const float*)d_in[1];
  const float* prek = (const float*)d_in[2];
  const float* W    = (const float*)d_in[3];
  const float* kck  = (const float*)d_in[4];
  const float* kcb  = (const float*)d_in[5];
  const float* vck  = (const float*)d_in[6];
  const float* vcb  = (const float*)d_in[7];
  const int*   msk  = (const int*)d_in[8];
  float* out = (float*)d_out;

  char* ws = (char*)d_ws;
  unsigned short* WT  = (unsigned short*)(ws);                      // 2 MB
  unsigned short* kcB = (unsigned short*)(ws + 2162688);            // 4 MB  [bh][c][dh]
  unsigned short* vcT = (unsigned short*)(ws + 6356992);            // 4 MB  [bh][dh][c]
  unsigned short* mrg = (unsigned short*)(ws + 10551296);           // 16 MB [8192][1024]
  unsigned int*   mpk = (unsigned int*)(ws + 27328512);             // 512 KB packed mask

  hipLaunchKernelGGL(pre_kernel, dim3(1792), dim3(256), 0, stream,
                     prek, kck, kcb, kcB, prev, vck, vcb, vcT, W, WT, msk, mpk);
  hipLaunchKernelGGL(attn_kernel, dim3(1024), dim3(256), 0, stream, preq, mpk, kcB, vcT, mrg);
  hipLaunchKernelGGL(gemm_kernel, dim3(1024), dim3(256), 0, stream, mrg, WT, out);
}

// Round 17
// 90.491 us; speedup vs baseline: 1.1887x; 1.1887x over previous
//
#include <hip/hip_runtime.h>
#include <hip/hip_bf16.h>

// Problem constants (fixed by setup_inputs): B=4, S=2048, H=16, DH=64, W=4,
// Kc=512, D=1024. Output (4,2048,1024) f32.

typedef __attribute__((ext_vector_type(8))) short short8;   // 8 bf16 (4 VGPRs)
typedef __attribute__((ext_vector_type(4))) short short4v;  // 4 bf16 (2 VGPRs)
typedef __attribute__((ext_vector_type(4))) float f32x4;
typedef __attribute__((ext_vector_type(4))) int int4e;
typedef __attribute__((ext_vector_type(2))) unsigned int u32x2;

#define MFMA32(A, Bf, C) __builtin_amdgcn_mfma_f32_16x16x32_bf16((A), (Bf), (C), 0, 0, 0)
#define MFMA16(A, Bf, C) __builtin_amdgcn_mfma_f32_16x16x16bf16_1k((A), (Bf), (C), 0, 0, 0)

static __device__ __forceinline__ unsigned short f2bf(float f) {
  unsigned int u = __builtin_bit_cast(unsigned int, f);
  u += 0x7fffu + ((u >> 16) & 1u);   // RNE (finite inputs only)
  return (unsigned short)(u >> 16);
}
static __device__ __forceinline__ unsigned int pack2c(float a, float b) {
  unsigned short lo = __builtin_bit_cast(unsigned short, __float2bfloat16(a));
  unsigned short hi = __builtin_bit_cast(unsigned short, __float2bfloat16(b));
  return (unsigned int)lo | ((unsigned int)hi << 16);
}
// 4x f32 -> 4x bf16 via packed-pair conversions (v_cvt_pk_bf16_f32)
static __device__ __forceinline__ short4v pk4(float a, float b, float c, float d) {
  u32x2 t;
  t[0] = pack2c(a, b);
  t[1] = pack2c(c, d);
  return __builtin_bit_cast(short4v, t);
}
// masked exp2: exp2(s) if bit set, else 0 — sign-extended bit AND.
static __device__ __forceinline__ float mexp2(float s, unsigned int w, int bit) {
  const unsigned int m = (unsigned int)(((int)(w << (31 - bit))) >> 31);
  const float e = __builtin_amdgcn_exp2f(s);
  return __builtin_bit_cast(float, __builtin_bit_cast(unsigned int, e) & m);
}
static __device__ __forceinline__ short8 cvt8(f32x4 lo, f32x4 hi) {
  short8 r;
  r[0] = (short)f2bf(lo[0]); r[1] = (short)f2bf(lo[1]);
  r[2] = (short)f2bf(lo[2]); r[3] = (short)f2bf(lo[3]);
  r[4] = (short)f2bf(hi[0]); r[5] = (short)f2bf(hi[1]);
  r[6] = (short)f2bf(hi[2]); r[7] = (short)f2bf(hi[3]);
  return r;
}
static __device__ __forceinline__ short8 cvt8s(f32x4 lo, f32x4 hi, float s) {
  short8 r;
  r[0] = (short)f2bf(lo[0]*s); r[1] = (short)f2bf(lo[1]*s);
  r[2] = (short)f2bf(lo[2]*s); r[3] = (short)f2bf(lo[3]*s);
  r[4] = (short)f2bf(hi[0]*s); r[5] = (short)f2bf(hi[1]*s);
  r[6] = (short)f2bf(hi[2]*s); r[7] = (short)f2bf(hi[3]*s);
  return r;
}
// async global -> LDS, 16B/lane; LDS dest is wave-uniform base + lane*16
static __device__ __forceinline__ void gl_lds16(const void* g, void* l) {
  __builtin_amdgcn_global_load_lds(
      (const __attribute__((address_space(1))) unsigned int*)g,
      (__attribute__((address_space(3))) unsigned int*)l, 16, 0, 0);
}

// ---------------------------------------------------------------------------
// 1) Fused pre: [0,1024) conv1d compression (self-transposing); [1024,1280)
// transpose W; [1280,1792) pack mask bits.
__global__ __launch_bounds__(256) void pre_kernel(
    const float* __restrict__ srcK, const float* __restrict__ kckRaw,
    const float* __restrict__ biasK, unsigned short* __restrict__ dstK,
    const float* __restrict__ srcV, const float* __restrict__ vckRaw,
    const float* __restrict__ biasV, unsigned short* __restrict__ dstV,
    const float* __restrict__ W, unsigned short* __restrict__ WT,
    const int* __restrict__ msk, unsigned int* __restrict__ mpk) {
  __shared__ unsigned short shm[21504];          // 43008 B
  const int bid = blockIdx.x;
  const int tid = threadIdx.x;
  if (bid < 1024) {
    const int tpose = bid >> 9;
    const float* src = tpose ? srcV : srcK;
    const float* kraw = tpose ? vckRaw : kckRaw;
    const float* bias = tpose ? biasV : biasK;
    unsigned short* dst = tpose ? dstV : dstK;
    unsigned short* kTl = shm;                   // [o=64][kk=256 pad 264]
    unsigned short* t = shm + 16896;             // [64][72] epilogue tile
    {
      const int o = tid & 63, m0 = tid >> 6;
      #pragma unroll
      for (int it = 0; it < 8; ++it) {
        const int kk0 = (it * 4 + m0) * 8;
        short8 v;
        #pragma unroll
        for (int s = 0; s < 8; ++s)
          v[s] = (short)f2bf(kraw[(size_t)(kk0 + s) * 64 + o]);
        *(short8*)(kTl + o * 264 + kk0) = v;
      }
    }
    __syncthreads();
    const int wid = tid >> 6, lane = tid & 63;
    const int q = lane & 15, g = lane >> 4;
    const int blockR0 = (bid & 511) * 64;
    const int R0 = blockR0 + wid * 16;
    const int row = R0 + q;
    const int bh = row >> 9, c = row & 511;
    const int b = bh >> 4, h = bh & 15;
    const float* sb = src + (((size_t)b * 2048 + (size_t)c * 4) * 16 + h) * 64;
    f32x4 acc[4];
    #pragma unroll
    for (int ct = 0; ct < 4; ++ct) acc[ct] = f32x4{0.f, 0.f, 0.f, 0.f};
    #pragma unroll
    for (int ch = 0; ch < 8; ++ch) {
      const int kk = ch * 32 + g * 8;
      const int w = kk >> 6, i = kk & 63;
      const float* s8 = sb + (size_t)w * 1024 + i;
      short8 a = cvt8(*(const f32x4*)s8, *(const f32x4*)(s8 + 4));
      #pragma unroll
      for (int ct = 0; ct < 4; ++ct) {
        short8 bf = *(const short8*)(kTl + (ct * 16 + q) * 264 + ch * 32 + g * 8);
        acc[ct] = MFMA32(a, bf, acc[ct]);
      }
    }
    #pragma unroll
    for (int ct = 0; ct < 4; ++ct) {
      const int col = ct * 16 + q;
      const float bv = bias[col];
      #pragma unroll
      for (int r = 0; r < 4; ++r) {
        const int lr = wid * 16 + 4 * g + r;
        const unsigned short val = f2bf(acc[ct][r] + bv);
        t[tpose ? (col * 72 + lr) : (lr * 72 + col)] = val;
      }
    }
    __syncthreads();
    const int d = tid >> 2, sq = tid & 3;
    const short8 w0 = *(const short8*)(&t[d * 72 + sq * 16]);
    const short8 w1 = *(const short8*)(&t[d * 72 + sq * 16 + 8]);
    unsigned short* op;
    if (tpose) {
      const int bhb = blockR0 >> 9, cb = blockR0 & 511;
      op = dst + (size_t)bhb * 32768 + (size_t)d * 512 + cb + sq * 16;
    } else {
      op = dst + (size_t)(blockR0 + d) * 64 + sq * 16;
    }
    *(short8*)op = w0;
    *(short8*)(op + 8) = w1;
  } else if (bid < 1280) {
    unsigned short (*t2)[72] = (unsigned short (*)[72])shm;
    const int wb = bid - 1024;
    const int k0 = (wb & 15) * 64, n0 = (wb >> 4) * 64;
    const int cr = tid >> 4, cc = (tid & 15) * 4;
    #pragma unroll
    for (int it = 0; it < 4; ++it) {
      const int kk = it * 16 + cr;
      const f32x4 v = *(const f32x4*)(W + (size_t)(k0 + kk) * 1024 + n0 + cc);
      #pragma unroll
      for (int j = 0; j < 4; ++j) t2[cc + j][kk] = f2bf(v[j]);
    }
    __syncthreads();
    const int rn = tid >> 2, seg = tid & 3;
    const short8 w0 = *(const short8*)(&t2[rn][seg * 16]);
    const short8 w1 = *(const short8*)(&t2[rn][seg * 16 + 8]);
    unsigned short* op = WT + (size_t)(n0 + rn) * 1024 + k0 + seg * 16;
    *(short8*)op = w0;
    *(short8*)(op + 8) = w1;
  } else {
    const int w = (bid - 1280) * 256 + tid;
    const int* p = msk + (size_t)w * 32;
    unsigned int b = 0;
    #pragma unroll
    for (int i = 0; i < 8; ++i) {
      const int4e v = *(const int4e*)(p + i * 4);
      b |= (unsigned int)(v[0] & 1) << (i * 4);
      b |= (unsigned int)(v[1] & 1) << (i * 4 + 1);
      b |= (unsigned int)(v[2] & 1) << (i * 4 + 2);
      b |= (unsigned int)(v[3] & 1) << (i * 4 + 3);
    }
    mpk[w] = b;
  }
}

// ---------------------------------------------------------------------------
// 3) Attention v16 (measured 47.7us): 64-key superchunks, K/V reg-staged dbuf
// LDS, P in registers (K=16 PV), ones-MFMA sums, bfe/and masked-exp.
__global__ __launch_bounds__(256) void attn_kernel(
    const float* __restrict__ preq, const unsigned int* __restrict__ mpk,
    const unsigned short* __restrict__ kc, const unsigned short* __restrict__ vt,
    unsigned short* __restrict__ merged) {
  __shared__ unsigned short shm[18432];   // 36864 B: K 2x4608sh | V 2x4608sh
  unsigned short* Kl = shm;
  unsigned short* Vl = shm + 9216;
  const int tid = threadIdx.x;
  const int wid = tid >> 6, lane = tid & 63;
  const int q = lane & 15, g = lane >> 4;
  const int bid = blockIdx.x;
  const int x = bid & 7, ii = bid >> 3;
  const int bp = x >> 1;
  const int hp = ((x & 1) << 3) | (ii & 7);
  const int tile = ii >> 3;
  const int jj = hp * 4 + bp;
  const int bin = jj >> 4, hin = jj & 15;
  const int s0 = tile * 128 + wid * 32;

  const float QS = 0.18033688f;    // 0.125 * log2(e)
  const float* qpA = preq + (((size_t)bin * 2048 + s0 + q) * 16 + hin) * 64;
  const float* qpB = qpA + 16 * 1024;
  const short8 bqA0 = cvt8s(*(const f32x4*)(qpA + g * 8), *(const f32x4*)(qpA + g * 8 + 4), QS);
  const short8 bqA1 = cvt8s(*(const f32x4*)(qpA + 32 + g * 8), *(const f32x4*)(qpA + 32 + g * 8 + 4), QS);
  const short8 bqB0 = cvt8s(*(const f32x4*)(qpB + g * 8), *(const f32x4*)(qpB + g * 8 + 4), QS);
  const short8 bqB1 = cvt8s(*(const f32x4*)(qpB + 32 + g * 8), *(const f32x4*)(qpB + 32 + g * 8 + 4), QS);

  const unsigned short* kcb = kc + (size_t)jj * 512 * 64;
  const unsigned short* vtb = vt + (size_t)(bp * 16 + hp) * 64 * 512;
  const unsigned int* mrowA = mpk + ((size_t)bp * 2048 + s0 + q) * 16;
  const unsigned int* mrowB = mrowA + 256;

  const int sr = tid >> 3, sseg = tid & 7;
  const unsigned short* gK0 = kcb + (size_t)sr * 64 + sseg * 8;
  const unsigned short* gK1 = gK0 + 32 * 64;
  unsigned short* lK0 = Kl + sr * 72 + sseg * 8;
  unsigned short* lK1 = lK0 + 32 * 72;
  const unsigned short* gV0 = vtb + (size_t)sr * 512 + sseg * 8;
  const unsigned short* gV1 = gV0 + 32 * 512;
  unsigned short* lV0 = Vl + sr * 72 + sseg * 8;
  unsigned short* lV1 = lV0 + 32 * 72;

  const short4v one4 = {(short)0x3F80, (short)0x3F80, (short)0x3F80, (short)0x3F80};

  f32x4 oA[4], oB[4];
  #pragma unroll
  for (int o = 0; o < 4; ++o) { oA[o] = f32x4{0,0,0,0}; oB[o] = f32x4{0,0,0,0}; }
  f32x4 oSA = {0,0,0,0}, oSB = {0,0,0,0};

  *(short8*)lK0 = *(const short8*)gK0;
  *(short8*)lK1 = *(const short8*)gK1;
  *(short8*)lV0 = *(const short8*)gV0;
  *(short8*)lV1 = *(const short8*)gV1;
  u32x2 mA2 = *(const u32x2*)mrowA;
  u32x2 mB2 = *(const u32x2*)mrowB;
  __syncthreads();

  #pragma unroll 2
  for (int sc = 0; sc < 8; ++sc) {
    short8 nK0, nK1, nV0, nV1;
    u32x2 nmA = {0, 0}, nmB = {0, 0};
    if (sc < 7) {
      nK0 = *(const short8*)(gK0 + (size_t)(sc + 1) * 4096);
      nK1 = *(const short8*)(gK1 + (size_t)(sc + 1) * 4096);
      nV0 = *(const short8*)(gV0 + (sc + 1) * 64);
      nV1 = *(const short8*)(gV1 + (sc + 1) * 64);
      nmA = *(const u32x2*)(mrowA + 2 * (sc + 1));
      nmB = *(const u32x2*)(mrowB + 2 * (sc + 1));
    }
    const unsigned short* Kc_ = Kl + (sc & 1) * 4608;
    const unsigned short* Vc_ = Vl + (sc & 1) * 4608;
    __builtin_amdgcn_s_setprio(1);
    short4v pA[4], pB[4];
    #pragma unroll
    for (int sub = 0; sub < 4; ++sub) {
      const short8 k0 = *(const short8*)(Kc_ + (sub * 16 + q) * 72 + g * 8);
      const short8 k1 = *(const short8*)(Kc_ + (sub * 16 + q) * 72 + 32 + g * 8);
      f32x4 sA = {0,0,0,0}; sA = MFMA32(k0, bqA0, sA); sA = MFMA32(k1, bqA1, sA);
      f32x4 sB = {0,0,0,0}; sB = MFMA32(k0, bqB0, sB); sB = MFMA32(k1, bqB1, sB);
      const unsigned int wA = mA2[sub >> 1], wB = mB2[sub >> 1];
      const int bb = (sub & 1) * 16 + 4 * g;
      float eA[4], eB[4];
      #pragma unroll
      for (int r = 0; r < 4; ++r) {
        eA[r] = mexp2(sA[r], wA, bb + r);
        eB[r] = mexp2(sB[r], wB, bb + r);
      }
      pA[sub] = pk4(eA[0], eA[1], eA[2], eA[3]);
      pB[sub] = pk4(eB[0], eB[1], eB[2], eB[3]);
    }
    #pragma unroll
    for (int o = 0; o < 4; ++o) {
      #pragma unroll
      for (int sub = 0; sub < 4; ++sub) {
        const short4v vfr = *(const short4v*)(Vc_ + (o * 16 + q) * 72 + sub * 16 + g * 4);
        oA[o] = MFMA16(vfr, pA[sub], oA[o]);
        oB[o] = MFMA16(vfr, pB[sub], oB[o]);
      }
    }
    #pragma unroll
    for (int sub = 0; sub < 4; ++sub) {
      oSA = MFMA16(one4, pA[sub], oSA);
      oSB = MFMA16(one4, pB[sub], oSB);
    }
    __builtin_amdgcn_s_setprio(0);
    if (sc < 7) {
      const int nb = ((sc + 1) & 1) * 4608;
      *(short8*)(lK0 + nb) = nK0;
      *(short8*)(lK1 + nb) = nK1;
      *(short8*)(lV0 + nb) = nV0;
      *(short8*)(lV1 + nb) = nV1;
    }
    __syncthreads();
    mA2 = nmA; mB2 = nmB;
  }

  const float rlA = 1.0f / oSA[0], rlB = 1.0f / oSB[0];

  unsigned short* eb = shm + wid * 2304;
  #pragma unroll
  for (int qs = 0; qs < 2; ++qs) {
    unsigned int* U = (unsigned int*)(eb + qs * 1152);
    const float rl = qs ? rlB : rlA;
    #pragma unroll
    for (int o = 0; o < 4; ++o) {
      const f32x4 ov = qs ? oB[o] : oA[o];
      U[q * 36 + o * 8 + 2 * g]     = pack2c(ov[0] * rl, ov[1] * rl);
      U[q * 36 + o * 8 + 2 * g + 1] = pack2c(ov[2] * rl, ov[3] * rl);
    }
  }
  const int ir = lane >> 2, sg2 = lane & 3;
  #pragma unroll
  for (int qs = 0; qs < 2; ++qs) {
    const unsigned short* ep = eb + qs * 1152;
    const short8 w0 = *(const short8*)(ep + ir * 72 + sg2 * 16);
    const short8 w1 = *(const short8*)(ep + ir * 72 + sg2 * 16 + 8);
    unsigned short* mp = merged + ((size_t)(bp * 2048 + s0 + qs * 16 + ir)) * 1024 + hp * 64 + sg2 * 16;
    *(short8*)mp = w0;
    *(short8*)(mp + 8) = w1;
  }
}

// ---------------------------------------------------------------------------
// 4) Output projection — REVERTED to R14/R15 (measured-best inside the 91.3us
// total): 128x128 tiles, grid 512, 4-buffer distance-2 pipeline, one barrier
// per 2 k-steps. R16's 128x64 tile halved compute-per-barrier and stalled
// (VALUBusy 4.3%) — compute-per-barrier is the quantity to protect.
__global__ __launch_bounds__(256) void gemm_kernel(
    const unsigned short* __restrict__ A, const unsigned short* __restrict__ BT,
    float* __restrict__ out) {
  __shared__ unsigned short Bb[4][4096];   // 4 x 8KB k-step buffers, XOR-swizzled
  const int tid = threadIdx.x;
  const int wid = tid >> 6, lane = tid & 63;
  const int q = lane & 15, g = lane >> 4;
  const int bid = blockIdx.x;
  const int x = bid & 7, i = bid >> 3;
  const int N0 = (i & 7) * 128;
  const int M0 = (x * 8 + (i >> 3)) * 128 + wid * 32;

  const int r0 = wid * 32 + (lane >> 2);
  const int r1 = r0 + 16;
  const int sc = (lane & 3) * 16;
  const int b0 = sc ^ (((r0 >> 2) & 3) << 4);
  const int b1 = sc ^ (((r1 >> 2) & 3) << 4);
  const unsigned short* gs0 = BT + (size_t)(N0 + r0) * 1024 + (b0 >> 1);
  const unsigned short* gs1 = BT + (size_t)(N0 + r1) * 1024 + (b1 >> 1);
  const int bsz = ((q >> 2) & 3) << 4;

  f32x4 acc[2][8];
  #pragma unroll
  for (int rt = 0; rt < 2; ++rt)
    #pragma unroll
    for (int ct = 0; ct < 8; ++ct) acc[rt][ct] = f32x4{0.f, 0.f, 0.f, 0.f};
  const unsigned short* a0p = A + (size_t)(M0 + q) * 1024 + g * 8;
  const unsigned short* a1p = a0p + 16 * 1024;

  gl_lds16(gs0,      &Bb[0][wid * 1024]);
  gl_lds16(gs1,      &Bb[0][wid * 1024 + 512]);
  gl_lds16(gs0 + 32, &Bb[1][wid * 1024]);
  gl_lds16(gs1 + 32, &Bb[1][wid * 1024 + 512]);
  short8 aC00 = *(const short8*)(a0p);
  short8 aC01 = *(const short8*)(a1p);
  short8 aC10 = *(const short8*)(a0p + 32);
  short8 aC11 = *(const short8*)(a1p + 32);
  __syncthreads();

  for (int t = 0; t < 32; t += 2) {
    if (t < 30) {
      gl_lds16(gs0 + (t + 2) * 32, &Bb[(t + 2) & 3][wid * 1024]);
      gl_lds16(gs1 + (t + 2) * 32, &Bb[(t + 2) & 3][wid * 1024 + 512]);
      gl_lds16(gs0 + (t + 3) * 32, &Bb[(t + 3) & 3][wid * 1024]);
      gl_lds16(gs1 + (t + 3) * 32, &Bb[(t + 3) & 3][wid * 1024 + 512]);
    }
    short8 aN00 = aC00, aN01 = aC01, aN10 = aC10, aN11 = aC11;
    if (t < 30) {
      aN00 = *(const short8*)(a0p + (t + 2) * 32);
      aN01 = *(const short8*)(a1p + (t + 2) * 32);
      aN10 = *(const short8*)(a0p + (t + 3) * 32);
      aN11 = *(const short8*)(a1p + (t + 3) * 32);
    }
    const unsigned short* Bc0 = &Bb[t & 3][0];
    const unsigned short* Bc1 = &Bb[(t + 1) & 3][0];
    #pragma unroll
    for (int ct = 0; ct < 8; ++ct) {
      const int off = (ct * 16 + q) * 32 + (((g * 16) ^ bsz) >> 1);
      const short8 bfr0 = *(const short8*)(Bc0 + off);
      acc[0][ct] = MFMA32(aC00, bfr0, acc[0][ct]);
      acc[1][ct] = MFMA32(aC01, bfr0, acc[1][ct]);
      const short8 bfr1 = *(const short8*)(Bc1 + off);
      acc[0][ct] = MFMA32(aC10, bfr1, acc[0][ct]);
      acc[1][ct] = MFMA32(aC11, bfr1, acc[1][ct]);
    }
    aC00 = aN00; aC01 = aN01; aC10 = aN10; aC11 = aN11;
    __syncthreads();
  }
  #pragma unroll
  for (int rt = 0; rt < 2; ++rt)
    #pragma unroll
    for (int ct = 0; ct < 8; ++ct)
      #pragma unroll
      for (int r = 0; r < 4; ++r)
        out[(size_t)(M0 + rt * 16 + 4 * g + r) * 1024 + N0 + ct * 16 + q] = acc[rt][ct][r];
}

// ---------------------------------------------------------------------------
extern "C" void kernel_launch(void* const* d_in, const int* in_sizes, int n_in,
                              void* d_out, int out_size, void* d_ws, size_t ws_size,
                              hipStream_t stream) {
  const float* preq = (const float*)d_in[0];
  const float* prev = (const float*)d_in[1];
  const float* prek = (const float*)d_in[2];
  const float* W    = (const float*)d_in[3];
  const float* kck  = (const float*)d_in[4];
  const float* kcb  = (const float*)d_in[5];
  const float* vck  = (const float*)d_in[6];
  const float* vcb  = (const float*)d_in[7];
  const int*   msk  = (const int*)d_in[8];
  float* out = (float*)d_out;

  char* ws = (char*)d_ws;
  unsigned short* WT  = (unsigned short*)(ws);                      // 2 MB
  unsigned short* kcB = (unsigned short*)(ws + 2162688);            // 4 MB  [bh][c][dh]
  unsigned short* vcT = (unsigned short*)(ws + 6356992);            // 4 MB  [bh][dh][c]
  unsigned short* mrg = (unsigned short*)(ws + 10551296);           // 16 MB [8192][1024]
  unsigned int*   mpk = (unsigned int*)(ws + 27328512);             // 512 KB packed mask

  hipLaunchKernelGGL(pre_kernel, dim3(1792), dim3(256), 0, stream,
                     prek, kck, kcb, kcB, prev, vck, vcb, vcT, W, WT, msk, mpk);
  hipLaunchKernelGGL(attn_kernel, dim3(1024), dim3(256), 0, stream, preq, mpk, kcB, vcT, mrg);
  hipLaunchKernelGGL(gemm_kernel, dim3(512), dim3(256), 0, stream, mrg, WT, out);
}